// Round 11
// baseline (48.468 us; speedup 1.0000x reference)
//
#include <hip/hip_runtime.h>
#include <math.h>

// Problem constants: z [4,32,32,32] f32, embedding [32768,32] f32.
constexpr int Bc   = 4;
constexpr int Dc   = 32;
constexpr int HWc  = 1024;
constexpr int NE   = 32768;
constexpr int POS  = Bc * HWc;        // 4096 positions

constexpr int CCODES = 256;           // codes per block chunk (32 KB in LDS)
constexpr int NCHUNK = NE / CCODES;   // 128
constexpr int NPBLK  = 16;            // pos-blocks of 256 positions

typedef _Float16 f16x8 __attribute__((ext_vector_type(8)));
typedef float    f32x4 __attribute__((ext_vector_type(4)));
typedef unsigned long long u64;

// Monotonic float->uint encoding; pack with ~idx so that among equal values
// the SMALLER index wins under max (== jnp.argmax first-index rule).
__device__ inline u64 packVI(float v, int idx) {
    unsigned u = __float_as_uint(v);
    u = (u & 0x80000000u) ? ~u : (u | 0x80000000u);
    return ((u64)u << 32) | (unsigned)(~idx);
}

// Prep: split-fp16 conversion. Blocks 0..127: embedding -> Es [32768][64]
// (hi dims 0..31, lo dims 32..63; hi+lo = x to ~2^-22). Blocks 128..143:
// z -> Zs [4096][64] in the SAME layout (so vq_mfma A-frags are plain 16B
// loads, killing ~150 convert ops per wave), and zero best[].
__global__ __launch_bounds__(256) void vq_eprep(
    const float* __restrict__ emb, const float* __restrict__ z,
    _Float16* __restrict__ Es, _Float16* __restrict__ Zs,
    u64* __restrict__ best)
{
    float x[Dc];
    _Float16* dptr;
    if (blockIdx.x < NE / 256) {
        const int c = blockIdx.x * 256 + threadIdx.x;       // 0..32767
        const float4* src = reinterpret_cast<const float4*>(emb + (size_t)c * Dc);
#pragma unroll
        for (int q = 0; q < 8; ++q) {
            const float4 v = src[q];
            x[4*q+0] = v.x; x[4*q+1] = v.y; x[4*q+2] = v.z; x[4*q+3] = v.w;
        }
        dptr = Es + (size_t)c * 64;
    } else {
        const int p = (blockIdx.x - NE / 256) * 256 + threadIdx.x;  // 0..4095
        best[p] = 0ULL;            // encoded minimum: any real value wins
        const int b = p >> 10, hw = p & (HWc - 1);
        const float* zp = z + (size_t)b * Dc * HWc + hw;
#pragma unroll
        for (int d = 0; d < Dc; ++d) x[d] = zp[(size_t)d * HWc];
        dptr = Zs + (size_t)p * 64;
    }
    f16x8* dst = reinterpret_cast<f16x8*>(dptr);
#pragma unroll
    for (int q = 0; q < 4; ++q) {
        f16x8 h, l;
#pragma unroll
        for (int r = 0; r < 8; ++r) {
            const float xv = x[8*q+r];
            const _Float16 hv = (_Float16)xv;
            h[r] = hv;
            l[r] = (_Float16)(xv - (float)hv);
        }
        dst[q]     = h;   // hi block
        dst[4 + q] = l;   // lo block
    }
}

// Main: split-fp16 MFMA (hi*hi + hi*lo + lo*hi; bit-identical to rounds
// 8-10, absmax 0). Round-11: VALU diet. (1) acc init via persistent pinned
// ZACC quad as the C-operand (no per-tile zeroing). (2) epilogue
// cmp+cndmask+v_max = 3 ops/logit. (3) wave-reduce tail replaced by an
// LDS-transposed merge (reuses elds after a barrier; frees the 32-reg pk
// butterfly peak). (4) A-frags are plain 16B loads from preconverted Zs.
// Staging + swizzle identical to round 10 (measured conflict-free).
__global__ __launch_bounds__(256, 4) void vq_mfma(
    const _Float16* __restrict__ Zs, const _Float16* __restrict__ Es,
    u64* __restrict__ best)
{
    __shared__ __align__(16) _Float16 elds[CCODES * 64];   // 32 KB

    const int lin  = blockIdx.x;               // 0..2047
    const int xcd  = lin & 7;                  // dispatch round-robins XCDs
    const int j    = lin >> 3;                 // 0..255
    const int chunk = xcd * (NCHUNK / 8) + (j & (NCHUNK / 8 - 1));
    const int pblk  = j >> 4;                  // 0..15
    const int tid  = threadIdx.x;
    const int wave = tid >> 6, lane = tid & 63;
    const int m = lane & 15, g = lane >> 4;

    // ---- stage chunk -> LDS via global_load_lds, source pre-swizzled ----
    {
        const char* src = (const char*)(Es + (size_t)chunk * CCODES * 64);
        char* dstbase = (char*)elds + wave * 1024;   // wave-uniform base
#pragma unroll
        for (int r = 0; r < 8; ++r) {
            const int o    = r * 256 + tid;          // 16B-chunk index
            const int row  = o >> 3;                 // code row 0..255
            const int ccol = o & 7;                  // 16B col 0..7
            const int soff = row * 128 + ((ccol ^ (row & 7)) << 4);
            __builtin_amdgcn_global_load_lds(
                (const __attribute__((address_space(1))) void*)(src + soff),
                (__attribute__((address_space(3))) void*)(dstbase + r * 4096),
                16, 0, 0);
        }
    }

    // ---- A fragments: plain 16B loads from preconverted Zs ----
    const int posBase0 = pblk * 256;
    const int posBase  = posBase0 + wave * 64;
    f16x8 Ahi[4], Alo[4];
#pragma unroll
    for (int t = 0; t < 4; ++t) {
        const _Float16* zrow = Zs + (size_t)(posBase + t * 16 + m) * 64 + 8 * g;
        Ahi[t] = *reinterpret_cast<const f16x8*>(zrow);
        Alo[t] = *reinterpret_cast<const f16x8*>(zrow + 32);
    }
#pragma unroll
    for (int t = 0; t < 4; ++t) asm volatile("" : "+v"(Ahi[t]), "+v"(Alo[t]));

    f32x4 zacc = {0.f, 0.f, 0.f, 0.f};
    asm volatile("" : "+v"(zacc));     // persistent zero C-operand quad

    float bval[16];
    int   bidx[16];
#pragma unroll
    for (int i = 0; i < 16; ++i) { bval[i] = -INFINITY; bidx[i] = 0; }

    __syncthreads();   // staging complete

    // ---- scan 16 code-tiles from LDS ----
    const int cbase = chunk * CCODES;
    const char* lbase = (const char*)elds;
    int bh_off = m * 128 + (( g      ^ (m & 7)) << 4);
    int bl_off = m * 128 + (((g + 4) ^ (m & 7)) << 4);
    int idxv = cbase + m;

#pragma unroll 2
    for (int ct = 0; ct < CCODES / 16; ++ct) {
        const f16x8 Bh = *reinterpret_cast<const f16x8*>(lbase + bh_off);
        const f16x8 Bl = *reinterpret_cast<const f16x8*>(lbase + bl_off);
        bh_off += 2048; bl_off += 2048;

#pragma unroll
        for (int t = 0; t < 4; ++t) {
            f32x4 acc;
            acc = __builtin_amdgcn_mfma_f32_16x16x32_f16(Ahi[t], Bh, zacc, 0, 0, 0);
            acc = __builtin_amdgcn_mfma_f32_16x16x32_f16(Ahi[t], Bl, acc,  0, 0, 0);
            acc = __builtin_amdgcn_mfma_f32_16x16x32_f16(Alo[t], Bh, acc,  0, 0, 0);
#pragma unroll
            for (int r = 0; r < 4; ++r) {
                const int i = t * 4 + r;
                const bool up = acc[r] > bval[i];       // strict '>': first idx
                bidx[i] = up ? idxv : bidx[i];          // v_cndmask
                bval[i] = fmaxf(bval[i], acc[r]);       // v_max_f32
            }
        }
        idxv += 16;
    }

    // ---- tail: LDS-transposed merge (reuse elds), 1 thread = 1 position ----
    __syncthreads();                       // all waves done reading B
    u64* cand = reinterpret_cast<u64*>(elds);   // 256 rows x 16 slots = 32 KB
    // element (t,r) of lane (g,m) belongs to position-row tid_r:
    //   tid_r = wave*64 + t*16 + 4g + r ; slot m, XOR-swizzled for banks.
#pragma unroll
    for (int i = 0; i < 16; ++i) {
        const int t = i >> 2, r = i & 3;
        const int tid_r = wave * 64 + t * 16 + 4 * g + r;
        cand[tid_r * 16 + (m ^ (tid_r & 15))] = packVI(bval[i], bidx[i]);
    }
    __syncthreads();
    u64 bu = 0;
#pragma unroll
    for (int mm = 0; mm < 16; ++mm) {
        const u64 v = cand[tid * 16 + (mm ^ (tid & 15))];
        if (v > bu) bu = v;
    }
    atomicMax(best + posBase0 + tid, bu);
}

// Fallback (ws too small): scalar VALU scan, all 256 segments.
__global__ __launch_bounds__(256, 4) void vq_scalar(
    const float* __restrict__ z, const float* __restrict__ emb,
    u64* __restrict__ best)
{
    const int lin = blockIdx.x;           // 0..2047
    const int xcd = lin & 7, j = lin >> 3;
    const int seg    = xcd * 32 + (j & 31);
    const int posgrp = j >> 5;

    const int t  = posgrp * 256 + threadIdx.x;
    const int p0 = t, p1 = t + POS / 2;
    const int b0 = p0 >> 10, hw0 = p0 & (HWc - 1);
    const int b1 = p1 >> 10, hw1 = p1 & (HWc - 1);
    const float* zp0 = z + (size_t)b0 * Dc * HWc + hw0;
    const float* zp1 = z + (size_t)b1 * Dc * HWc + hw1;

    float za[Dc], zb[Dc];
#pragma unroll
    for (int d = 0; d < Dc; ++d) {
        za[d] = zp0[(size_t)d * HWc];
        zb[d] = zp1[(size_t)d * HWc];
    }
#pragma unroll
    for (int d = 0; d < Dc; ++d) asm volatile("" : "+v"(za[d]), "+v"(zb[d]));

    const int c0 = seg * 128;
    const float4* e4 = reinterpret_cast<const float4*>(emb + (size_t)c0 * Dc);
    float v0 = -INFINITY, v1 = -INFINITY;
    int   i0 = c0, i1 = c0;
#pragma unroll 1
    for (int cc = 0; cc < 128; ++cc, e4 += 8) {
        float a0 = 0.f, a1 = 0.f;
#pragma unroll
        for (int q = 0; q < 8; ++q) {
            const float4 e = e4[q];
            a0 = fmaf(za[4*q+0], e.x, a0); a1 = fmaf(zb[4*q+0], e.x, a1);
            a0 = fmaf(za[4*q+1], e.y, a0); a1 = fmaf(zb[4*q+1], e.y, a1);
            a0 = fmaf(za[4*q+2], e.z, a0); a1 = fmaf(zb[4*q+2], e.z, a1);
            a0 = fmaf(za[4*q+3], e.w, a0); a1 = fmaf(zb[4*q+3], e.w, a1);
        }
        const int c = c0 + cc;
        if (a0 > v0) { v0 = a0; i0 = c; }
        if (a1 > v1) { v1 = a1; i1 = c; }
    }
    atomicMax(best + p0, packVI(v0, i0));
    atomicMax(best + p1, packVI(v1, i1));
}

// Finish: decode winner, gather embedding row (float4, exact fp32 values),
// write z_q [b,d,h,w] coalesced, index as float (<=32767 exact in fp32).
__global__ __launch_bounds__(256) void vq_finish_kernel(
    const u64* __restrict__ best, const float* __restrict__ emb,
    float* __restrict__ zq, float* __restrict__ indOut)
{
    const int p = blockIdx.x * 256 + threadIdx.x;
    const u64 pk = best[p];
    const int idx = (int)(~(unsigned)pk);

    const float4* e = reinterpret_cast<const float4*>(emb + (size_t)idx * Dc);
    const int b  = p >> 10;
    const int hw = p & (HWc - 1);
    float* o = zq + (size_t)b * Dc * HWc + hw;
#pragma unroll
    for (int q = 0; q < 8; ++q) {
        const float4 v = e[q];
        o[(size_t)(4*q+0) * HWc] = v.x;
        o[(size_t)(4*q+1) * HWc] = v.y;
        o[(size_t)(4*q+2) * HWc] = v.z;
        o[(size_t)(4*q+3) * HWc] = v.w;
    }
    indOut[p] = (float)idx;
}

extern "C" void kernel_launch(void* const* d_in, const int* in_sizes, int n_in,
                              void* d_out, int out_size, void* d_ws, size_t ws_size,
                              hipStream_t stream)
{
    const float* z   = (const float*)d_in[0];
    const float* emb = (const float*)d_in[1];

    float* out    = (float*)d_out;
    float* zq     = out;                          // 131072 floats
    float* indOut = out + (size_t)Bc * Dc * HWc;  // 4096 index values (as f32)

    u64* best = (u64*)d_ws;                                      // 32 KB
    _Float16* Es = (_Float16*)((char*)d_ws + (size_t)POS * 8);   // 4 MB
    _Float16* Zs = Es + (size_t)NE * 64;                         // 512 KB
    const size_t needed = (size_t)POS * 8 + (size_t)(NE + POS) * 64 * 2;

    if (ws_size >= needed) {
        hipLaunchKernelGGL(vq_eprep, dim3(NE / 256 + POS / 256), dim3(256), 0,
                           stream, emb, z, Es, Zs, best);
        hipLaunchKernelGGL(vq_mfma, dim3(NCHUNK * NPBLK), dim3(256), 0, stream,
                           Zs, Es, best);
    } else {
        hipMemsetAsync(best, 0, (size_t)POS * sizeof(u64), stream);
        hipLaunchKernelGGL(vq_scalar, dim3(2048), dim3(256), 0, stream,
                           z, emb, best);
    }
    hipLaunchKernelGGL(vq_finish_kernel, dim3(POS / 256), dim3(256), 0, stream,
                       best, emb, zq, indOut);
}

// Round 12
// 47.527 us; speedup vs baseline: 1.0198x; 1.0198x over previous
//
#include <hip/hip_runtime.h>
#include <math.h>

// Problem constants: z [4,32,32,32] f32, embedding [32768,32] f32.
constexpr int Bc   = 4;
constexpr int Dc   = 32;
constexpr int HWc  = 1024;
constexpr int NE   = 32768;
constexpr int POS  = Bc * HWc;        // 4096 positions

constexpr int CCODES = 256;           // codes per block chunk (32 KB in LDS)
constexpr int NCHUNK = NE / CCODES;   // 128
constexpr int NPBLK  = 16;            // pos-blocks of 256 positions

typedef _Float16 f16x8 __attribute__((ext_vector_type(8)));
typedef float    f32x4 __attribute__((ext_vector_type(4)));
typedef unsigned long long u64;

// Monotonic float->uint encoding; pack with ~idx so that among equal values
// the SMALLER index wins under max (== jnp.argmax first-index rule).
__device__ inline u64 packVI(float v, int idx) {
    unsigned u = __float_as_uint(v);
    u = (u & 0x80000000u) ? ~u : (u | 0x80000000u);
    return ((u64)u << 32) | (unsigned)(~idx);
}

// Single main kernel (no eprep): stage RAW fp32 embedding chunk -> LDS,
// convert in-LDS to split-fp16 (hi+lo = x to ~2^-21; same 32 KB footprint),
// then the validated split-fp16 MFMA scan (hi*hi + hi*lo + lo*hi; absmax 0
// in rounds 8-11). VALU diet vs r11: best-tile id (bct, 4 bits) tracked by
// cndmask against the wave-uniform tile counter instead of a per-lane idxv
// register; index reconstructed once in the tail. Tail merge via LDS rows of
// 17 u64 (136 B: bank varies with row; r11's 128 B stride was bank-invariant
// -> 262K conflicts). Staging/read swizzle identical to r10 (measured 0
// conflicts).
__global__ __launch_bounds__(256, 4) void vq_mfma(
    const float* __restrict__ z, const float* __restrict__ emb,
    u64* __restrict__ best)
{
    __shared__ __align__(16) char lds[CCODES * 17 * 8];   // 34.8 KB (tail pad)

    const int lin  = blockIdx.x;               // 0..2047
    const int xcd  = lin & 7;                  // dispatch round-robins XCDs
    const int j    = lin >> 3;                 // 0..255
    const int chunk = xcd * (NCHUNK / 8) + (j & (NCHUNK / 8 - 1));
    const int pblk  = j >> 4;                  // 0..15
    const int tid  = threadIdx.x;
    const int wave = tid >> 6, lane = tid & 63;
    const int m = lane & 15, g = lane >> 4;

    // ---- stage raw fp32 chunk -> LDS via global_load_lds, pre-swizzled ----
    // LDS[row][col16B] = src[row][col ^ (row&7)]  (XOR involution)
    {
        const char* src = (const char*)(emb + (size_t)chunk * CCODES * Dc);
        char* dstbase = lds + wave * 1024;           // wave-uniform base
#pragma unroll
        for (int r = 0; r < 8; ++r) {
            const int o    = r * 256 + tid;          // 16B-chunk index
            const int row  = o >> 3;                 // code row 0..255
            const int ccol = o & 7;                  // 16B col 0..7
            const int soff = row * 128 + ((ccol ^ (row & 7)) << 4);
            __builtin_amdgcn_global_load_lds(
                (const __attribute__((address_space(1))) void*)(src + soff),
                (__attribute__((address_space(3))) void*)(dstbase + r * 4096),
                16, 0, 0);
        }
    }

    // ---- A fragments from z, split-fp16 in regs (overlaps staging) ----
    const int posBase0 = pblk * 256;
    const int posBase  = posBase0 + wave * 64;
    f16x8 Ahi[4], Alo[4];
#pragma unroll
    for (int t = 0; t < 4; ++t) {
        const int pos = posBase + t * 16 + m;
        const int b = pos >> 10, hw = pos & (HWc - 1);
        const float* zp = z + (size_t)b * Dc * HWc + hw;
#pragma unroll
        for (int q = 0; q < 8; ++q) {
            const float xv = zp[(size_t)(8 * g + q) * HWc];
            const _Float16 hv = (_Float16)xv;
            Ahi[t][q] = hv;
            Alo[t][q] = (_Float16)(xv - (float)hv);
        }
    }
#pragma unroll
    for (int t = 0; t < 4; ++t) asm volatile("" : "+v"(Ahi[t]), "+v"(Alo[t]));

    f32x4 zacc = {0.f, 0.f, 0.f, 0.f};
    asm volatile("" : "+v"(zacc));     // persistent zero C-operand quad

    float bval[16];
    int   bct[16];
#pragma unroll
    for (int i = 0; i < 16; ++i) { bval[i] = -INFINITY; bct[i] = 0; }

    __syncthreads();   // staging complete

    // ---- in-LDS convert: thread t owns row t (read own row, write own row;
    //      2-way bank aliasing only, which is free) ----
    {
        char* myrow = lds + tid * 128;
        float4 raw[8];
#pragma unroll
        for (int c = 0; c < 8; ++c)
            raw[c] = *reinterpret_cast<const float4*>(myrow + ((c ^ (tid & 7)) << 4));
        f16x8 h[4], l[4];
#pragma unroll
        for (int cc = 0; cc < 4; ++cc) {
            const float4 a = raw[2 * cc], b = raw[2 * cc + 1];
            const float xs[8] = {a.x, a.y, a.z, a.w, b.x, b.y, b.z, b.w};
#pragma unroll
            for (int r = 0; r < 8; ++r) {
                const _Float16 hv = (_Float16)xs[r];
                h[cc][r] = hv;
                l[cc][r] = (_Float16)(xs[r] - (float)hv);
            }
        }
#pragma unroll
        for (int cc = 0; cc < 4; ++cc) {
            *reinterpret_cast<f16x8*>(myrow + (( cc      ^ (tid & 7)) << 4)) = h[cc];
            *reinterpret_cast<f16x8*>(myrow + (((cc + 4) ^ (tid & 7)) << 4)) = l[cc];
        }
    }
    __syncthreads();   // convert complete

    // ---- hot loop: 16 code-tiles from LDS ----
    const int cbase = chunk * CCODES;
    const char* lbase = lds;
    int bh_off = m * 128 + (( g      ^ (m & 7)) << 4);
    int bl_off = m * 128 + (((g + 4) ^ (m & 7)) << 4);

#pragma unroll 2
    for (int ct = 0; ct < CCODES / 16; ++ct) {
        const f16x8 Bh = *reinterpret_cast<const f16x8*>(lbase + bh_off);
        const f16x8 Bl = *reinterpret_cast<const f16x8*>(lbase + bl_off);
        bh_off += 2048; bl_off += 2048;

#pragma unroll
        for (int t = 0; t < 4; ++t) {
            f32x4 acc;
            acc = __builtin_amdgcn_mfma_f32_16x16x32_f16(Ahi[t], Bh, zacc, 0, 0, 0);
            acc = __builtin_amdgcn_mfma_f32_16x16x32_f16(Ahi[t], Bl, acc,  0, 0, 0);
            acc = __builtin_amdgcn_mfma_f32_16x16x32_f16(Alo[t], Bh, acc,  0, 0, 0);
#pragma unroll
            for (int r = 0; r < 4; ++r) {
                const int i = t * 4 + r;
                const bool up = acc[r] > bval[i];   // strict '>': first tile
                bct[i]  = up ? ct : bct[i];         // cndmask, SGPR ct
                bval[i] = fmaxf(bval[i], acc[r]);   // v_max_f32
            }
        }
    }

    // ---- tail: LDS merge, rows of 17 u64 (bank varies with row) ----
    __syncthreads();                    // all waves done reading B
    u64* cand = reinterpret_cast<u64*>(lds);
#pragma unroll
    for (int i = 0; i < 16; ++i) {
        const int t = i >> 2, r = i & 3;
        const int row = wave * 64 + t * 16 + 4 * g + r;
        const int idx = cbase + bct[i] * 16 + m;
        cand[row * 17 + m] = packVI(bval[i], idx);
    }
    __syncthreads();
    u64 bu = 0;
#pragma unroll
    for (int mm = 0; mm < 16; ++mm) {
        const u64 v = cand[tid * 17 + mm];
        if (v > bu) bu = v;
    }
    atomicMax(best + posBase0 + tid, bu);
}

// Finish: decode winner, gather embedding row (float4, exact fp32 values),
// write z_q [b,d,h,w] coalesced, index as float (<=32767 exact in fp32).
__global__ __launch_bounds__(256) void vq_finish_kernel(
    const u64* __restrict__ best, const float* __restrict__ emb,
    float* __restrict__ zq, float* __restrict__ indOut)
{
    const int p = blockIdx.x * 256 + threadIdx.x;
    const u64 pk = best[p];
    const int idx = (int)(~(unsigned)pk);

    const float4* e = reinterpret_cast<const float4*>(emb + (size_t)idx * Dc);
    const int b  = p >> 10;
    const int hw = p & (HWc - 1);
    float* o = zq + (size_t)b * Dc * HWc + hw;
#pragma unroll
    for (int q = 0; q < 8; ++q) {
        const float4 v = e[q];
        o[(size_t)(4*q+0) * HWc] = v.x;
        o[(size_t)(4*q+1) * HWc] = v.y;
        o[(size_t)(4*q+2) * HWc] = v.z;
        o[(size_t)(4*q+3) * HWc] = v.w;
    }
    indOut[p] = (float)idx;
}

extern "C" void kernel_launch(void* const* d_in, const int* in_sizes, int n_in,
                              void* d_out, int out_size, void* d_ws, size_t ws_size,
                              hipStream_t stream)
{
    const float* z   = (const float*)d_in[0];
    const float* emb = (const float*)d_in[1];

    float* out    = (float*)d_out;
    float* zq     = out;                          // 131072 floats
    float* indOut = out + (size_t)Bc * Dc * HWc;  // 4096 index values (as f32)

    u64* best = (u64*)d_ws;                       // 32 KB

    // encoded 0 == minimum of the monotonic ordering -> any real value wins
    hipMemsetAsync(best, 0, (size_t)POS * sizeof(u64), stream);

    hipLaunchKernelGGL(vq_mfma, dim3(NCHUNK * NPBLK), dim3(256), 0, stream,
                       z, emb, best);
    hipLaunchKernelGGL(vq_finish_kernel, dim3(POS / 256), dim3(256), 0, stream,
                       best, emb, zq, indOut);
}